// Round 2
// baseline (455.668 us; speedup 1.0000x reference)
//
#include <hip/hip_runtime.h>
#include <hip/hip_fp16.h>

#define DD 128            // emb dim, fixed by problem
#define SCAN_CHUNK 1024   // elements per scan1 block
#define ROWS_PER_BLK 16   // rows per gather block (16 lanes/row * 16 rows = 256)
#define MAX_STAGE 512     // staged edges per gather block (mean 256, +16 sigma)

typedef float          f32x4 __attribute__((ext_vector_type(4)));
typedef unsigned int   u32x4 __attribute__((ext_vector_type(4)));
typedef unsigned int   u32x2 __attribute__((ext_vector_type(2)));
typedef unsigned short u16x8 __attribute__((ext_vector_type(8)));

struct __align__(8) Edge { int c; float v; };

// ---- fp16 helpers ----
__device__ __forceinline__ unsigned short f2h(float f) {
    return __half_as_ushort(__float2half(f));
}
__device__ __forceinline__ float2 up2(unsigned int u) {
    __half2 h = *reinterpret_cast<const __half2*>(&u);
    return __half22float2(h);
}

// ---- non-temporal access helpers (keep L2/L3 for the gather working set) ----
template <typename T>
__device__ __forceinline__ T ldnt(const T* p) { return __builtin_nontemporal_load(p); }
template <typename T>
__device__ __forceinline__ void stnt(T* p, T v) { __builtin_nontemporal_store(v, p); }

// ---- CSR build ----------------------------------------------------------

__global__ __launch_bounds__(256) void k_zero(int* __restrict__ p, int n) {
    int i = blockIdx.x * 256 + threadIdx.x;
    if (i < n) p[i] = 0;
}

// fused: [0, prepBlocks) = dense prep (g1/emb16/mask2), [prepBlocks, ...) = hist.
// Overlaps hist's atomic latency under prep's streaming bandwidth.
__global__ __launch_bounds__(256) void k_prep(const float* __restrict__ emb,
                                              const float* __restrict__ u1,
                                              const float* __restrict__ u2,
                                              ushort* __restrict__ g1,
                                              ushort* __restrict__ emb16,
                                              unsigned char* __restrict__ mask2,
                                              int total8, int prepBlocks,
                                              const int* __restrict__ rows,
                                              int* __restrict__ cnt, int E) {
    if ((int)blockIdx.x < prepBlocks) {
        int i = blockIdx.x * 256 + threadIdx.x;
        if (i >= total8) return;
        const f32x4* e4 = (const f32x4*)emb;
        const f32x4* a4 = (const f32x4*)u1;
        const f32x4* b4 = (const f32x4*)u2;
        f32x4 hA = ldnt(e4 + 2 * (size_t)i);
        f32x4 hB = ldnt(e4 + 2 * (size_t)i + 1);
        f32x4 uA = ldnt(a4 + 2 * (size_t)i);
        f32x4 uB = ldnt(a4 + 2 * (size_t)i + 1);
        f32x4 vA = ldnt(b4 + 2 * (size_t)i);
        f32x4 vB = ldnt(b4 + 2 * (size_t)i + 1);
        const float s = 1.0f / 0.9f;
        u16x8 g;
        g[0] = f2h((uA.x >= 0.1f) ? hA.x * s : 0.0f);
        g[1] = f2h((uA.y >= 0.1f) ? hA.y * s : 0.0f);
        g[2] = f2h((uA.z >= 0.1f) ? hA.z * s : 0.0f);
        g[3] = f2h((uA.w >= 0.1f) ? hA.w * s : 0.0f);
        g[4] = f2h((uB.x >= 0.1f) ? hB.x * s : 0.0f);
        g[5] = f2h((uB.y >= 0.1f) ? hB.y * s : 0.0f);
        g[6] = f2h((uB.z >= 0.1f) ? hB.z * s : 0.0f);
        g[7] = f2h((uB.w >= 0.1f) ? hB.w * s : 0.0f);
        ((u16x8*)g1)[i] = g;   // normal store: gather1's working set
        u16x8 e16;
        e16[0] = f2h(hA.x); e16[1] = f2h(hA.y); e16[2] = f2h(hA.z); e16[3] = f2h(hA.w);
        e16[4] = f2h(hB.x); e16[5] = f2h(hB.y); e16[6] = f2h(hB.z); e16[7] = f2h(hB.w);
        stnt((u16x8*)emb16 + i, e16);
        unsigned char m =
            (unsigned char)((vA.x >= 0.1f ? 1u : 0u)  | (vA.y >= 0.1f ? 2u : 0u)  |
                            (vA.z >= 0.1f ? 4u : 0u)  | (vA.w >= 0.1f ? 8u : 0u)  |
                            (vB.x >= 0.1f ? 16u : 0u) | (vB.y >= 0.1f ? 32u : 0u) |
                            (vB.z >= 0.1f ? 64u : 0u) | (vB.w >= 0.1f ? 128u : 0u));
        stnt(mask2 + i, m);
    } else {
        int e = ((int)blockIdx.x - prepBlocks) * 256 + threadIdx.x;
        if (e < E) {
            int r = ldnt(rows + e);
            atomicAdd(&cnt[r], 1);   // result unused -> non-returning atomic
        }
    }
}

// per-block exclusive scan of 1024 elements (4/thread), block totals -> bsum
__global__ __launch_bounds__(256) void k_scan1(int* __restrict__ data,
                                               int* __restrict__ bsum, int n) {
    __shared__ int s[256];
    int tid = threadIdx.x;
    int base = blockIdx.x * SCAN_CHUNK + tid * 4;
    int v0 = 0, v1 = 0, v2 = 0, v3 = 0;
    if (base + 0 < n) v0 = data[base + 0];
    if (base + 1 < n) v1 = data[base + 1];
    if (base + 2 < n) v2 = data[base + 2];
    if (base + 3 < n) v3 = data[base + 3];
    int tsum = v0 + v1 + v2 + v3;
    s[tid] = tsum;
    __syncthreads();
    for (int off = 1; off < 256; off <<= 1) {
        int t = (tid >= off) ? s[tid - off] : 0;
        __syncthreads();
        s[tid] += t;
        __syncthreads();
    }
    int excl = s[tid] - tsum;
    if (tid == 255) bsum[blockIdx.x] = s[255];
    if (base + 0 < n) data[base + 0] = excl;
    if (base + 1 < n) data[base + 1] = excl + v0;
    if (base + 2 < n) data[base + 2] = excl + v0 + v1;
    if (base + 3 < n) data[base + 3] = excl + v0 + v1 + v2;
}

// fused scan2+scan3 + cursor copy: block offset add, writes rowstart (in-place)
// and a second cursor copy for the atomic scatter.
__global__ __launch_bounds__(256) void k_scan23(int* __restrict__ data,
                                                const int* __restrict__ bsum,
                                                int* __restrict__ cursor,
                                                int nb, int n) {
    __shared__ int s[1024];
    int tid = threadIdx.x;
    for (int i = tid; i < nb; i += 256) s[i] = bsum[i];
    __syncthreads();
    if (tid == 0) {
        int run = 0;
        for (int i = 0; i < nb; ++i) { int t = s[i]; s[i] = run; run += t; }
    }
    __syncthreads();
    int i = blockIdx.x * 256 + tid;
    if (i < n) {
        int v = data[i] + s[i >> 10];
        data[i] = v;
        cursor[i] = v;
    }
}

// pos = atomicAdd(cursor[r]) -- no rank array; packed 8B write
__global__ __launch_bounds__(256) void k_scatter(const int* __restrict__ rows,
                                                 const int* __restrict__ cols,
                                                 const float* __restrict__ vals,
                                                 int* __restrict__ cursor,
                                                 Edge* __restrict__ ev, int E) {
    int e = blockIdx.x * 256 + threadIdx.x;
    if (e >= E) return;
    int r = ldnt(rows + e);
    int c = ldnt(cols + e);
    float v = ldnt(vals + e);
    int pos = atomicAdd(&cursor[r], 1);
    u32x2 q;
    q.x = (unsigned int)c;
    q.y = __float_as_uint(v);
    ((u32x2*)ev)[pos] = q;
}

// ---- gather SpMM --------------------------------------------------------
// 16 rows/block, 16 lanes/row, 8 halves (16B) per lane. Block's CSR edge
// range is contiguous -> cooperative LDS stage (1 barrier), then each group
// reads edges from LDS (broadcast) and issues gathers 8-deep uninterrupted.
// MODE 1: p16 = fp16(h1 = A*src); g2 = fp16(dropout(h1) via mask2 bits)
// MODE 2: out = (emb16 + p16in + A*src) / 3   [fp32]
template <int MODE>
__global__ __launch_bounds__(256) void k_gather(const int* __restrict__ rowstart,
                                                const Edge* __restrict__ ev,
                                                const ushort* __restrict__ srch,
                                                const unsigned char* __restrict__ mask2,
                                                const ushort* __restrict__ emb16,
                                                const ushort* __restrict__ p16in,
                                                ushort* __restrict__ p16out,
                                                ushort* __restrict__ g2,
                                                float* __restrict__ out,
                                                int N, int E) {
    __shared__ int s_rs[ROWS_PER_BLK + 1];
    __shared__ Edge s_ev[MAX_STAGE];

    int tid = threadIdx.x;
    int r0 = blockIdx.x * ROWS_PER_BLK;
    if (tid <= ROWS_PER_BLK) {
        int r = r0 + tid;
        s_rs[tid] = (r < N) ? rowstart[r] : E;
    }
    __syncthreads();
    int base = s_rs[0];
    int nblk = s_rs[ROWS_PER_BLK] - base;
    int nstage = nblk < MAX_STAGE ? nblk : MAX_STAGE;
    for (int i = tid; i < nstage; i += 256) {
        u32x2 q = ldnt((const u32x2*)(ev + base + i));
        Edge ed; ed.c = (int)q.x; ed.v = __uint_as_float(q.y);
        s_ev[i] = ed;
    }
    __syncthreads();

    int grp = tid >> 4;
    int lane = tid & 15;
    int row = r0 + grp;
    if (row >= N) return;
    int start = s_rs[grp] - base;
    int end = s_rs[grp + 1] - base;
    int eL = end < nstage ? end : nstage;

    const u32x4* __restrict__ s4 = (const u32x4*)srch;  // 8 halves per u32x4
    const Edge* __restrict__ evg = ev + base;
    float a0 = 0.f, a1 = 0.f, a2 = 0.f, a3 = 0.f;
    float a4 = 0.f, a5 = 0.f, a6 = 0.f, a7 = 0.f;

#define LDE(i) Edge E##i = s_ev[e + i];
#define GQ(i)  u32x4 q##i = s4[((size_t)E##i.c << 4) + lane];
#define ACC(i) { float vv = E##i.v; \
        float2 w0 = up2(q##i.x), w1 = up2(q##i.y), w2 = up2(q##i.z), w3 = up2(q##i.w); \
        a0 = fmaf(vv, w0.x, a0); a1 = fmaf(vv, w0.y, a1); \
        a2 = fmaf(vv, w1.x, a2); a3 = fmaf(vv, w1.y, a3); \
        a4 = fmaf(vv, w2.x, a4); a5 = fmaf(vv, w2.y, a5); \
        a6 = fmaf(vv, w3.x, a6); a7 = fmaf(vv, w3.y, a7); }

    int e = start;
    for (; e + 8 <= eL; e += 8) {
        LDE(0) LDE(1) LDE(2) LDE(3) LDE(4) LDE(5) LDE(6) LDE(7)
        GQ(0) GQ(1) GQ(2) GQ(3) GQ(4) GQ(5) GQ(6) GQ(7)
        ACC(0) ACC(1) ACC(2) ACC(3) ACC(4) ACC(5) ACC(6) ACC(7)
    }
    if (e + 4 <= eL) {
        LDE(0) LDE(1) LDE(2) LDE(3)
        GQ(0) GQ(1) GQ(2) GQ(3)
        ACC(0) ACC(1) ACC(2) ACC(3)
        e += 4;
    }
    for (; e < eL; ++e) {
        LDE(0) GQ(0) ACC(0)
    }
    // rare spill: block had >MAX_STAGE edges; finish from global
    for (; e < end; ++e) {
        Edge E0; { u32x2 q_ = ldnt((const u32x2*)(evg + e));
                   E0.c = (int)q_.x; E0.v = __uint_as_float(q_.y); }
        GQ(0) ACC(0)
    }
#undef LDE
#undef GQ
#undef ACC

    size_t o = ((size_t)row << 7) + (size_t)lane * 8;
    if (MODE == 1) {
        unsigned int m = ldnt(mask2 + (size_t)row * 16 + lane);
        const float s = 1.0f / 0.9f;
        u16x8 gg;
        gg[0] = (m & 1u)   ? f2h(a0 * s) : (ushort)0;
        gg[1] = (m & 2u)   ? f2h(a1 * s) : (ushort)0;
        gg[2] = (m & 4u)   ? f2h(a2 * s) : (ushort)0;
        gg[3] = (m & 8u)   ? f2h(a3 * s) : (ushort)0;
        gg[4] = (m & 16u)  ? f2h(a4 * s) : (ushort)0;
        gg[5] = (m & 32u)  ? f2h(a5 * s) : (ushort)0;
        gg[6] = (m & 64u)  ? f2h(a6 * s) : (ushort)0;
        gg[7] = (m & 128u) ? f2h(a7 * s) : (ushort)0;
        stnt((u16x8*)(g2 + o), gg);
        u16x8 pp;
        pp[0] = f2h(a0); pp[1] = f2h(a1); pp[2] = f2h(a2); pp[3] = f2h(a3);
        pp[4] = f2h(a4); pp[5] = f2h(a5); pp[6] = f2h(a6); pp[7] = f2h(a7);
        stnt((u16x8*)(p16out + o), pp);
    } else {
        u32x4 eq = ldnt((const u32x4*)(emb16 + o));
        u32x4 pq = ldnt((const u32x4*)(p16in + o));
        float2 e0 = up2(eq.x), e1 = up2(eq.y), e2 = up2(eq.z), e3 = up2(eq.w);
        float2 p0 = up2(pq.x), p1 = up2(pq.y), p2 = up2(pq.z), p3 = up2(pq.w);
        const float t3 = 1.0f / 3.0f;
        f32x4 rA, rB;
        rA.x = (e0.x + p0.x + a0) * t3;
        rA.y = (e0.y + p0.y + a1) * t3;
        rA.z = (e1.x + p1.x + a2) * t3;
        rA.w = (e1.y + p1.y + a3) * t3;
        rB.x = (e2.x + p2.x + a4) * t3;
        rB.y = (e2.y + p2.y + a5) * t3;
        rB.z = (e3.x + p3.x + a6) * t3;
        rB.w = (e3.y + p3.y + a7) * t3;
        stnt((f32x4*)(out + o), rA);
        stnt((f32x4*)(out + o) + 1, rB);
    }
}

// ---- launch -------------------------------------------------------------

extern "C" void kernel_launch(void* const* d_in, const int* in_sizes, int n_in,
                              void* d_out, int out_size, void* d_ws, size_t ws_size,
                              hipStream_t stream) {
    const int* rows = (const int*)d_in[1];
    const int* cols = (const int*)d_in[2];
    const float* vals = (const float*)d_in[3];
    const float* emb = (const float*)d_in[4];
    const float* u1 = (const float*)d_in[5];
    const float* u2 = (const float*)d_in[6];
    float* out = (float*)d_out;

    const int N = in_sizes[0];
    const int E = in_sizes[1];
    const size_t ND = (size_t)N * DD;

    // workspace layout (~120 MB)
    char* ws = (char*)d_ws;
    Edge* ev     = (Edge*)ws;   ws += (size_t)E * sizeof(Edge);       // 12.8MB (8B align)
    ushort* g1   = (ushort*)ws; ws += ND * sizeof(ushort);            // 25.6MB fp16
    ushort* g2   = (ushort*)ws; ws += ND * sizeof(ushort);            // 25.6MB fp16
    ushort* p16  = (ushort*)ws; ws += ND * sizeof(ushort);            // 25.6MB fp16 h1
    ushort* emb16= (ushort*)ws; ws += ND * sizeof(ushort);            // 25.6MB fp16 emb
    int* cnt     = (int*)ws;    ws += (size_t)N * sizeof(int);        // -> rowstart
    int* cursor  = (int*)ws;    ws += (size_t)N * sizeof(int);
    int* bsum    = (int*)ws;    ws += 4096;
    unsigned char* mask2 = (unsigned char*)ws;                        // 1.6MB

    const int total8 = (int)(ND / 8);
    const int prepBlocks = (total8 + 255) / 256;
    const int gridE = (E + 255) / 256;
    const int gridN = (N + 255) / 256;
    const int nScanBlocks = (N + SCAN_CHUNK - 1) / SCAN_CHUNK;
    const int gridRow = (N + ROWS_PER_BLK - 1) / ROWS_PER_BLK;

    k_zero<<<gridN, 256, 0, stream>>>(cnt, N);
    // prep (g1/emb16/mask2) || hist, fused for overlap
    k_prep<<<prepBlocks + gridE, 256, 0, stream>>>(emb, u1, u2, g1, emb16, mask2,
                                                   total8, prepBlocks, rows, cnt, E);
    k_scan1<<<nScanBlocks, 256, 0, stream>>>(cnt, bsum, N);
    k_scan23<<<gridN, 256, 0, stream>>>(cnt, bsum, cursor, nScanBlocks, N);
    k_scatter<<<gridE, 256, 0, stream>>>(rows, cols, vals, cursor, ev, E);

    // h1 = A*g1; p16 = fp16(h1); g2 = fp16(dropout(h1, mask2))
    k_gather<1><<<gridRow, 256, 0, stream>>>(cnt, ev, g1, mask2, nullptr, nullptr,
                                             p16, g2, nullptr, N, E);
    // out = (emb16 + p16 + A*g2)/3
    k_gather<2><<<gridRow, 256, 0, stream>>>(cnt, ev, g2, nullptr, emb16, p16,
                                             nullptr, nullptr, out, N, E);
}

// Round 3
// 411.328 us; speedup vs baseline: 1.1078x; 1.1078x over previous
//
#include <hip/hip_runtime.h>
#include <hip/hip_fp16.h>

#define DD 128            // emb dim, fixed by problem
#define SCAN_CHUNK 1024   // elements per scan1 block
#define ROWS_PER_BLK 16   // rows per gather block (16 lanes/row * 16 rows = 256)
#define MAX_STAGE 512     // staged edges per gather block (mean 256, +16 sigma)

typedef float          f32x4 __attribute__((ext_vector_type(4)));
typedef unsigned int   u32x4 __attribute__((ext_vector_type(4)));
typedef unsigned int   u32x2 __attribute__((ext_vector_type(2)));
typedef unsigned short u16x8 __attribute__((ext_vector_type(8)));

struct __align__(8) Edge { int c; float v; };

// ---- fp16 helpers ----
__device__ __forceinline__ unsigned short f2h(float f) {
    return __half_as_ushort(__float2half(f));
}
__device__ __forceinline__ float2 up2(unsigned int u) {
    __half2 h = *reinterpret_cast<const __half2*>(&u);
    return __half22float2(h);
}

// ---- non-temporal access helpers (keep L2/L3 for the gather working set) ----
template <typename T>
__device__ __forceinline__ T ldnt(const T* p) { return __builtin_nontemporal_load(p); }
template <typename T>
__device__ __forceinline__ void stnt(T* p, T v) { __builtin_nontemporal_store(v, p); }

// ---- K1: g1 = fp16(dropout(emb,u1)) stream + per-thread hist edge ----------
// Thread-level fusion: the hist chain (load row -> returning atomic -> rank
// store) is independent of the streaming loads, so its latency hides under
// the bandwidth-bound g1 stream.
__global__ __launch_bounds__(256) void k_g1hist(const float* __restrict__ emb,
                                                const float* __restrict__ u1,
                                                ushort* __restrict__ g1,
                                                const int* __restrict__ rows,
                                                int* __restrict__ cnt,
                                                int* __restrict__ rank,
                                                int total8, int E) {
    int i = blockIdx.x * 256 + threadIdx.x;
    // hist edge (issue its load first; atomic depends only on it)
    if (i < E) {
        int r = ldnt(rows + i);
        int old = atomicAdd(&cnt[r], 1);
        stnt(rank + i, old);
    }
    // g1 stream
    if (i < total8) {
        const f32x4* e4 = (const f32x4*)emb;
        const f32x4* a4 = (const f32x4*)u1;
        f32x4 hA = ldnt(e4 + 2 * (size_t)i);
        f32x4 hB = ldnt(e4 + 2 * (size_t)i + 1);
        f32x4 uA = ldnt(a4 + 2 * (size_t)i);
        f32x4 uB = ldnt(a4 + 2 * (size_t)i + 1);
        const float s = 1.0f / 0.9f;
        u16x8 g;
        g[0] = f2h((uA.x >= 0.1f) ? hA.x * s : 0.0f);
        g[1] = f2h((uA.y >= 0.1f) ? hA.y * s : 0.0f);
        g[2] = f2h((uA.z >= 0.1f) ? hA.z * s : 0.0f);
        g[3] = f2h((uA.w >= 0.1f) ? hA.w * s : 0.0f);
        g[4] = f2h((uB.x >= 0.1f) ? hB.x * s : 0.0f);
        g[5] = f2h((uB.y >= 0.1f) ? hB.y * s : 0.0f);
        g[6] = f2h((uB.z >= 0.1f) ? hB.z * s : 0.0f);
        g[7] = f2h((uB.w >= 0.1f) ? hB.w * s : 0.0f);
        ((u16x8*)g1)[i] = g;   // normal store: gather1's working set
    }
}

// per-block exclusive scan of 1024 elements (4/thread), block totals -> bsum
__global__ __launch_bounds__(256) void k_scan1(int* __restrict__ data,
                                               int* __restrict__ bsum, int n) {
    __shared__ int s[256];
    int tid = threadIdx.x;
    int base = blockIdx.x * SCAN_CHUNK + tid * 4;
    int v0 = 0, v1 = 0, v2 = 0, v3 = 0;
    if (base + 0 < n) v0 = data[base + 0];
    if (base + 1 < n) v1 = data[base + 1];
    if (base + 2 < n) v2 = data[base + 2];
    if (base + 3 < n) v3 = data[base + 3];
    int tsum = v0 + v1 + v2 + v3;
    s[tid] = tsum;
    __syncthreads();
    for (int off = 1; off < 256; off <<= 1) {
        int t = (tid >= off) ? s[tid - off] : 0;
        __syncthreads();
        s[tid] += t;
        __syncthreads();
    }
    int excl = s[tid] - tsum;
    if (tid == 255) bsum[blockIdx.x] = s[255];
    if (base + 0 < n) data[base + 0] = excl;
    if (base + 1 < n) data[base + 1] = excl + v0;
    if (base + 2 < n) data[base + 2] = excl + v0 + v1;
    if (base + 3 < n) data[base + 3] = excl + v0 + v1 + v2;
}

// fused scan2+scan3: serial prefix of bsum (nb<=1024) in LDS, add block offset.
// data becomes rowstart.
__global__ __launch_bounds__(256) void k_scan23(int* __restrict__ data,
                                                const int* __restrict__ bsum,
                                                int nb, int n) {
    __shared__ int s[1024];
    int tid = threadIdx.x;
    for (int i = tid; i < nb; i += 256) s[i] = bsum[i];
    __syncthreads();
    if (tid == 0) {
        int run = 0;
        for (int i = 0; i < nb; ++i) { int t = s[i]; s[i] = run; run += t; }
    }
    __syncthreads();
    int i = blockIdx.x * 256 + tid;
    if (i < n) data[i] += s[i >> 10];
}

// ---- K4: rank-based edge scatter + emb16/mask2 stream ----------------------
// Scatter: pos = rowstart[r] + rank[e] (no atomic), independent loads + one
// random 8B store -> fully pipelined; latency hides under the emb16/mask2
// streaming bandwidth in the same wave.
__global__ __launch_bounds__(256) void k_scatter_prep(const int* __restrict__ rows,
                                                      const int* __restrict__ cols,
                                                      const float* __restrict__ vals,
                                                      const int* __restrict__ rowstart,
                                                      const int* __restrict__ rank,
                                                      Edge* __restrict__ ev,
                                                      const float* __restrict__ emb,
                                                      const float* __restrict__ u2,
                                                      ushort* __restrict__ emb16,
                                                      unsigned char* __restrict__ mask2,
                                                      int E, int total8) {
    int i = blockIdx.x * 256 + threadIdx.x;
    if (i < E) {
        int r = ldnt(rows + i);
        int c = ldnt(cols + i);
        float v = ldnt(vals + i);
        int rk = ldnt(rank + i);
        int pos = rowstart[r] + rk;   // rowstart is 400KB-hot, normal load
        u32x2 q;
        q.x = (unsigned int)c;
        q.y = __float_as_uint(v);
        ((u32x2*)ev)[pos] = q;        // normal store: L2/L3 absorbs amplification
    }
    if (i < total8) {
        const f32x4* e4 = (const f32x4*)emb;
        const f32x4* b4 = (const f32x4*)u2;
        f32x4 hA = ldnt(e4 + 2 * (size_t)i);
        f32x4 hB = ldnt(e4 + 2 * (size_t)i + 1);
        f32x4 vA = ldnt(b4 + 2 * (size_t)i);
        f32x4 vB = ldnt(b4 + 2 * (size_t)i + 1);
        u16x8 e16;
        e16[0] = f2h(hA.x); e16[1] = f2h(hA.y); e16[2] = f2h(hA.z); e16[3] = f2h(hA.w);
        e16[4] = f2h(hB.x); e16[5] = f2h(hB.y); e16[6] = f2h(hB.z); e16[7] = f2h(hB.w);
        stnt((u16x8*)emb16 + i, e16);
        unsigned char m =
            (unsigned char)((vA.x >= 0.1f ? 1u : 0u)  | (vA.y >= 0.1f ? 2u : 0u)  |
                            (vA.z >= 0.1f ? 4u : 0u)  | (vA.w >= 0.1f ? 8u : 0u)  |
                            (vB.x >= 0.1f ? 16u : 0u) | (vB.y >= 0.1f ? 32u : 0u) |
                            (vB.z >= 0.1f ? 64u : 0u) | (vB.w >= 0.1f ? 128u : 0u));
        stnt(mask2 + i, m);
    }
}

// ---- gather SpMM --------------------------------------------------------
// 16 rows/block, 16 lanes/row, 8 halves (16B) per lane. Block's CSR edge
// range is contiguous -> cooperative LDS stage (1 barrier), then each group
// reads edges from LDS (broadcast) and issues gathers 8-deep uninterrupted.
// MODE 1: p16 = fp16(h1 = A*src); g2 = fp16(dropout(h1) via mask2 bits)
// MODE 2: out = (emb16 + p16in + A*src) / 3   [fp32]
template <int MODE>
__global__ __launch_bounds__(256) void k_gather(const int* __restrict__ rowstart,
                                                const Edge* __restrict__ ev,
                                                const ushort* __restrict__ srch,
                                                const unsigned char* __restrict__ mask2,
                                                const ushort* __restrict__ emb16,
                                                const ushort* __restrict__ p16in,
                                                ushort* __restrict__ p16out,
                                                ushort* __restrict__ g2,
                                                float* __restrict__ out,
                                                int N, int E) {
    __shared__ int s_rs[ROWS_PER_BLK + 1];
    __shared__ Edge s_ev[MAX_STAGE];

    int tid = threadIdx.x;
    int r0 = blockIdx.x * ROWS_PER_BLK;
    if (tid <= ROWS_PER_BLK) {
        int r = r0 + tid;
        s_rs[tid] = (r < N) ? rowstart[r] : E;
    }
    __syncthreads();
    int base = s_rs[0];
    int nblk = s_rs[ROWS_PER_BLK] - base;
    int nstage = nblk < MAX_STAGE ? nblk : MAX_STAGE;
    for (int i = tid; i < nstage; i += 256) {
        u32x2 q = ldnt((const u32x2*)(ev + base + i));
        Edge ed; ed.c = (int)q.x; ed.v = __uint_as_float(q.y);
        s_ev[i] = ed;
    }
    __syncthreads();

    int grp = tid >> 4;
    int lane = tid & 15;
    int row = r0 + grp;
    if (row >= N) return;
    int start = s_rs[grp] - base;
    int end = s_rs[grp + 1] - base;
    int eL = end < nstage ? end : nstage;

    const u32x4* __restrict__ s4 = (const u32x4*)srch;  // 8 halves per u32x4
    const Edge* __restrict__ evg = ev + base;
    float a0 = 0.f, a1 = 0.f, a2 = 0.f, a3 = 0.f;
    float a4 = 0.f, a5 = 0.f, a6 = 0.f, a7 = 0.f;

#define LDE(i) Edge E##i = s_ev[e + i];
#define GQ(i)  u32x4 q##i = s4[((size_t)E##i.c << 4) + lane];
#define ACC(i) { float vv = E##i.v; \
        float2 w0 = up2(q##i.x), w1 = up2(q##i.y), w2 = up2(q##i.z), w3 = up2(q##i.w); \
        a0 = fmaf(vv, w0.x, a0); a1 = fmaf(vv, w0.y, a1); \
        a2 = fmaf(vv, w1.x, a2); a3 = fmaf(vv, w1.y, a3); \
        a4 = fmaf(vv, w2.x, a4); a5 = fmaf(vv, w2.y, a5); \
        a6 = fmaf(vv, w3.x, a6); a7 = fmaf(vv, w3.y, a7); }

    int e = start;
    for (; e + 8 <= eL; e += 8) {
        LDE(0) LDE(1) LDE(2) LDE(3) LDE(4) LDE(5) LDE(6) LDE(7)
        GQ(0) GQ(1) GQ(2) GQ(3) GQ(4) GQ(5) GQ(6) GQ(7)
        ACC(0) ACC(1) ACC(2) ACC(3) ACC(4) ACC(5) ACC(6) ACC(7)
    }
    if (e + 4 <= eL) {
        LDE(0) LDE(1) LDE(2) LDE(3)
        GQ(0) GQ(1) GQ(2) GQ(3)
        ACC(0) ACC(1) ACC(2) ACC(3)
        e += 4;
    }
    for (; e < eL; ++e) {
        LDE(0) GQ(0) ACC(0)
    }
    // rare spill: block had >MAX_STAGE edges; finish from global
    for (; e < end; ++e) {
        Edge E0; { u32x2 q_ = ldnt((const u32x2*)(evg + e));
                   E0.c = (int)q_.x; E0.v = __uint_as_float(q_.y); }
        GQ(0) ACC(0)
    }
#undef LDE
#undef GQ
#undef ACC

    size_t o = ((size_t)row << 7) + (size_t)lane * 8;
    if (MODE == 1) {
        unsigned int m = ldnt(mask2 + (size_t)row * 16 + lane);
        const float s = 1.0f / 0.9f;
        u16x8 gg;
        gg[0] = (m & 1u)   ? f2h(a0 * s) : (ushort)0;
        gg[1] = (m & 2u)   ? f2h(a1 * s) : (ushort)0;
        gg[2] = (m & 4u)   ? f2h(a2 * s) : (ushort)0;
        gg[3] = (m & 8u)   ? f2h(a3 * s) : (ushort)0;
        gg[4] = (m & 16u)  ? f2h(a4 * s) : (ushort)0;
        gg[5] = (m & 32u)  ? f2h(a5 * s) : (ushort)0;
        gg[6] = (m & 64u)  ? f2h(a6 * s) : (ushort)0;
        gg[7] = (m & 128u) ? f2h(a7 * s) : (ushort)0;
        stnt((u16x8*)(g2 + o), gg);
        u16x8 pp;
        pp[0] = f2h(a0); pp[1] = f2h(a1); pp[2] = f2h(a2); pp[3] = f2h(a3);
        pp[4] = f2h(a4); pp[5] = f2h(a5); pp[6] = f2h(a6); pp[7] = f2h(a7);
        stnt((u16x8*)(p16out + o), pp);
    } else {
        u32x4 eq = ldnt((const u32x4*)(emb16 + o));
        u32x4 pq = ldnt((const u32x4*)(p16in + o));
        float2 e0 = up2(eq.x), e1 = up2(eq.y), e2 = up2(eq.z), e3 = up2(eq.w);
        float2 p0 = up2(pq.x), p1 = up2(pq.y), p2 = up2(pq.z), p3 = up2(pq.w);
        const float t3 = 1.0f / 3.0f;
        f32x4 rA, rB;
        rA.x = (e0.x + p0.x + a0) * t3;
        rA.y = (e0.y + p0.y + a1) * t3;
        rA.z = (e1.x + p1.x + a2) * t3;
        rA.w = (e1.y + p1.y + a3) * t3;
        rB.x = (e2.x + p2.x + a4) * t3;
        rB.y = (e2.y + p2.y + a5) * t3;
        rB.z = (e3.x + p3.x + a6) * t3;
        rB.w = (e3.y + p3.y + a7) * t3;
        stnt((f32x4*)(out + o), rA);
        stnt((f32x4*)(out + o) + 1, rB);
    }
}

// ---- launch -------------------------------------------------------------

extern "C" void kernel_launch(void* const* d_in, const int* in_sizes, int n_in,
                              void* d_out, int out_size, void* d_ws, size_t ws_size,
                              hipStream_t stream) {
    const int* rows = (const int*)d_in[1];
    const int* cols = (const int*)d_in[2];
    const float* vals = (const float*)d_in[3];
    const float* emb = (const float*)d_in[4];
    const float* u1 = (const float*)d_in[5];
    const float* u2 = (const float*)d_in[6];
    float* out = (float*)d_out;

    const int N = in_sizes[0];
    const int E = in_sizes[1];
    const size_t ND = (size_t)N * DD;

    // workspace layout (~115 MB)
    char* ws = (char*)d_ws;
    Edge* ev     = (Edge*)ws;   ws += (size_t)E * sizeof(Edge);       // 12.8MB
    ushort* g1   = (ushort*)ws; ws += ND * sizeof(ushort);            // 25.6MB fp16
    ushort* g2   = (ushort*)ws; ws += ND * sizeof(ushort);            // 25.6MB fp16
    ushort* p16  = (ushort*)ws; ws += ND * sizeof(ushort);            // 25.6MB fp16 h1
    ushort* emb16= (ushort*)ws; ws += ND * sizeof(ushort);            // 25.6MB fp16 emb
    int* cnt     = (int*)ws;    ws += (size_t)N * sizeof(int);        // -> rowstart
    int* rank    = (int*)ws;    ws += (size_t)E * sizeof(int);        // 6.4MB
    int* bsum    = (int*)ws;    ws += 4096;
    unsigned char* mask2 = (unsigned char*)ws;                        // 1.6MB

    const int total8 = (int)(ND / 8);
    const int prepBlocks = (total8 + 255) / 256;
    const int gridE = (E + 255) / 256;
    const int gridFuse = prepBlocks > gridE ? prepBlocks : gridE;
    const int nScanBlocks = (N + SCAN_CHUNK - 1) / SCAN_CHUNK;
    const int gridRow = (N + ROWS_PER_BLK - 1) / ROWS_PER_BLK;

    hipMemsetAsync(cnt, 0, (size_t)N * sizeof(int), stream);
    // g1 stream + hist (thread-level fusion)
    k_g1hist<<<gridFuse, 256, 0, stream>>>(emb, u1, g1, rows, cnt, rank, total8, E);
    k_scan1<<<nScanBlocks, 256, 0, stream>>>(cnt, bsum, N);
    k_scan23<<<(N + 255) / 256, 256, 0, stream>>>(cnt, bsum, nScanBlocks, N);
    // rank-based scatter + emb16/mask2 stream (thread-level fusion)
    k_scatter_prep<<<gridFuse, 256, 0, stream>>>(rows, cols, vals, cnt, rank, ev,
                                                 emb, u2, emb16, mask2, E, total8);
    // h1 = A*g1; p16 = fp16(h1); g2 = fp16(dropout(h1, mask2))
    k_gather<1><<<gridRow, 256, 0, stream>>>(cnt, ev, g1, mask2, nullptr, nullptr,
                                             p16, g2, nullptr, N, E);
    // out = (emb16 + p16 + A*g2)/3
    k_gather<2><<<gridRow, 256, 0, stream>>>(cnt, ev, g2, nullptr, emb16, p16,
                                             nullptr, nullptr, out, N, E);
}